// Round 1
// baseline (559.818 us; speedup 1.0000x reference)
//
#include <hip/hip_runtime.h>
#include <hip/hip_bf16.h>
#include <stdint.h>

// LocalExperts grouped FFN: out[e] = relu(x[e] @ wi[e]) @ wo[e]
// E=8 experts, M=W*C=8192 tokens/expert, D=512, F=2048. fp32 in/out.
// Strategy: bf16 MFMA (16x16x32), fp32 accum. m97-style 128x128 tile GEMM.

#define E_N 8
#define W_N 8
#define C_N 1024
#define D_N 512
#define F_N 2048
#define ME  (W_N * C_N)   // 8192 rows per expert

typedef __attribute__((ext_vector_type(4))) float f32x4;
typedef __attribute__((ext_vector_type(8))) short s16x8;

__device__ __forceinline__ unsigned short f2bf(float f) {
  union { float f; unsigned int u; } v; v.f = f;
  unsigned int u = v.u + 0x7fffu + ((v.u >> 16) & 1u);  // RNE
  return (unsigned short)(u >> 16);
}

__device__ __forceinline__ void gload_lds16(void* lds, const void* g) {
  __builtin_amdgcn_global_load_lds(
      (const __attribute__((address_space(1))) unsigned int*)g,
      (__attribute__((address_space(3))) unsigned int*)lds, 16, 0, 0);
}

// Transpose + fp32->bf16: in [e][R][C] fp32 -> out [e][C][R] bf16
__global__ __launch_bounds__(256)
void transpose_cvt(const float* __restrict__ in, unsigned short* __restrict__ out,
                   int R, int Ccols) {
  __shared__ unsigned short tile[64][65];
  const int e = blockIdx.z;
  const float* ip = in + (size_t)e * R * Ccols;
  unsigned short* op = out + (size_t)e * R * Ccols;
  const int c0 = blockIdx.x * 64, r0 = blockIdx.y * 64;
  const int t = threadIdx.x;
  const int cl = (t & 15) * 4, rw = t >> 4;
#pragma unroll
  for (int i = 0; i < 4; ++i) {
    int row = rw + i * 16;
    float4 v = *(const float4*)&ip[(size_t)(r0 + row) * Ccols + c0 + cl];
    tile[row][cl + 0] = f2bf(v.x);
    tile[row][cl + 1] = f2bf(v.y);
    tile[row][cl + 2] = f2bf(v.z);
    tile[row][cl + 3] = f2bf(v.w);
  }
  __syncthreads();
#pragma unroll
  for (int i = 0; i < 4; ++i) {
    int oc = rw + i * 16;  // output row (= input col c0+oc)
    ushort4 o;
    o.x = tile[cl + 0][oc];
    o.y = tile[cl + 1][oc];
    o.z = tile[cl + 2][oc];
    o.w = tile[cl + 3][oc];
    *(ushort4*)&op[(size_t)(c0 + oc) * R + r0 + cl] = o;
  }
}

// fp32 -> bf16 elementwise (n multiple of 8)
__global__ __launch_bounds__(256)
void cvt_x_kernel(const float* __restrict__ in, unsigned short* __restrict__ out, size_t n) {
  size_t idx = ((size_t)blockIdx.x * 256 + threadIdx.x) * 8;
  const size_t stride = (size_t)gridDim.x * 256 * 8;
  for (; idx < n; idx += stride) {
    float4 a = *(const float4*)&in[idx];
    float4 b = *(const float4*)&in[idx + 4];
    union { s16x8 v; unsigned short u[8]; } p;
    p.u[0] = f2bf(a.x); p.u[1] = f2bf(a.y); p.u[2] = f2bf(a.z); p.u[3] = f2bf(a.w);
    p.u[4] = f2bf(b.x); p.u[5] = f2bf(b.y); p.u[6] = f2bf(b.z); p.u[7] = f2bf(b.w);
    *(s16x8*)&out[idx] = p.v;
  }
}

// C[M,N] = A[M,K] @ Bt[N,K]^T. A row-major K-contig, Bt row-major K-contig.
// 128x128 tile, BK=64, 256 threads = 4 waves (2x2), 64x64 per wave, 4x4 frags.
// A_IS_F32: stage A from fp32 with reg-convert; else global_load_lds from bf16.
// RELU_BF16_OUT: epilogue relu + bf16 store (h); else fp32 store.
template<bool A_IS_F32, bool RELU_BF16_OUT>
__global__ __launch_bounds__(256)
void gemm_bt(const void* __restrict__ Av, const unsigned short* __restrict__ BtBase,
             void* __restrict__ Cv, int N, int K,
             size_t aStrideE, size_t bStrideE, size_t cStrideE) {
  __shared__ unsigned short As[128 * 64];
  __shared__ unsigned short Bs[128 * 64];
  const int e = blockIdx.z;
  const int m0 = blockIdx.x * 128;
  const int n0 = blockIdx.y * 128;
  const int tid = threadIdx.x;
  const int lane = tid & 63;
  const int wave = tid >> 6;
  const int wr = (wave >> 1) * 64;
  const int wc = (wave & 1) * 64;
  const unsigned short* Bt = BtBase + (size_t)e * bStrideE;
  const float* Af = (const float*)Av + (size_t)e * aStrideE;
  const unsigned short* Ab = (const unsigned short*)Av + (size_t)e * aStrideE;

  f32x4 acc[4][4] = {};

  for (int k0 = 0; k0 < K; k0 += 64) {
    __syncthreads();  // previous tile's reads complete before overwrite
    if (A_IS_F32) {
#pragma unroll
      for (int i = 0; i < 4; ++i) {
        int ch = tid + 256 * i;            // 1024 chunks of 8 elems
        int row = ch >> 3, kc = ch & 7;
        const float* src = Af + (size_t)(m0 + row) * K + k0 + kc * 8;
        float4 a = *(const float4*)src;
        float4 b = *(const float4*)(src + 4);
        union { s16x8 v; unsigned short u[8]; } p;
        p.u[0] = f2bf(a.x); p.u[1] = f2bf(a.y); p.u[2] = f2bf(a.z); p.u[3] = f2bf(a.w);
        p.u[4] = f2bf(b.x); p.u[5] = f2bf(b.y); p.u[6] = f2bf(b.z); p.u[7] = f2bf(b.w);
        *(s16x8*)&As[row * 64 + kc * 8] = p.v;
      }
    } else {
#pragma unroll
      for (int i = 0; i < 4; ++i) {
        int seg = i * 4 + wave;            // 16 segments of 1024 B (8 rows)
        const unsigned short* src =
            Ab + (size_t)(m0 + seg * 8 + (lane >> 3)) * K + k0 + (lane & 7) * 8;
        gload_lds16(&As[seg * 512], src);  // LDS dest: base + lane*16 (linear)
      }
    }
#pragma unroll
    for (int i = 0; i < 4; ++i) {
      int seg = i * 4 + wave;
      const unsigned short* src =
          Bt + (size_t)(n0 + seg * 8 + (lane >> 3)) * K + k0 + (lane & 7) * 8;
      gload_lds16(&Bs[seg * 512], src);
    }
    __syncthreads();  // drains vmcnt(0)+lgkmcnt(0): staging visible
#pragma unroll
    for (int ks = 0; ks < 2; ++ks) {
      s16x8 af[4], bfr[4];
#pragma unroll
      for (int i = 0; i < 4; ++i)
        af[i] = *(const s16x8*)&As[(wr + i * 16 + (lane & 15)) * 64 + ks * 32 + (lane >> 4) * 8];
#pragma unroll
      for (int j = 0; j < 4; ++j)
        bfr[j] = *(const s16x8*)&Bs[(wc + j * 16 + (lane & 15)) * 64 + ks * 32 + (lane >> 4) * 8];
#pragma unroll
      for (int i = 0; i < 4; ++i)
#pragma unroll
        for (int j = 0; j < 4; ++j)
          acc[i][j] = __builtin_amdgcn_mfma_f32_16x16x32_bf16(af[i], bfr[j], acc[i][j], 0, 0, 0);
    }
  }

  // C/D layout (m89/m91): col = lane&15, row = (lane>>4)*4 + reg
  const int rq = (lane >> 4) * 4;
  const int cq = lane & 15;
  if (RELU_BF16_OUT) {
    unsigned short* Cb = (unsigned short*)Cv + (size_t)e * cStrideE;
#pragma unroll
    for (int i = 0; i < 4; ++i)
#pragma unroll
      for (int j = 0; j < 4; ++j) {
        int rbase = m0 + wr + i * 16 + rq;
        int col = n0 + wc + j * 16 + cq;
#pragma unroll
        for (int r = 0; r < 4; ++r) {
          float v = acc[i][j][r];
          v = v > 0.f ? v : 0.f;
          Cb[(size_t)(rbase + r) * N + col] = f2bf(v);
        }
      }
  } else {
    float* Cf = (float*)Cv + (size_t)e * cStrideE;
#pragma unroll
    for (int i = 0; i < 4; ++i)
#pragma unroll
      for (int j = 0; j < 4; ++j) {
        int rbase = m0 + wr + i * 16 + rq;
        int col = n0 + wc + j * 16 + cq;
#pragma unroll
        for (int r = 0; r < 4; ++r)
          Cf[(size_t)(rbase + r) * N + col] = acc[i][j][r];
      }
  }
}

// Zero-workspace fp32 fallback (correct, slow). One block per token row.
__global__ __launch_bounds__(256)
void fused_naive(const float* __restrict__ x, const float* __restrict__ wi,
                 const float* __restrict__ wo, float* __restrict__ out) {
  __shared__ float xs[D_N];
  __shared__ float hs[F_N];
  const size_t row = blockIdx.x;
  const int e = (int)(row / (W_N * C_N));
  const float* xr = x + row * D_N;
  const float* wie = wi + (size_t)e * D_N * F_N;
  const float* woe = wo + (size_t)e * F_N * D_N;
  const int t = threadIdx.x;
  for (int d = t; d < D_N; d += 256) xs[d] = xr[d];
  __syncthreads();
  for (int f = t; f < F_N; f += 256) {
    float a = 0.f;
    for (int d = 0; d < D_N; ++d) a += xs[d] * wie[(size_t)d * F_N + f];
    hs[f] = a > 0.f ? a : 0.f;
  }
  __syncthreads();
  float* orow = out + row * D_N;
  for (int d = t; d < D_N; d += 256) {
    float a = 0.f;
    for (int f = 0; f < F_N; ++f) a += hs[f] * woe[(size_t)f * D_N + d];
    orow[d] = a;
  }
}

extern "C" void kernel_launch(void* const* d_in, const int* in_sizes, int n_in,
                              void* d_out, int out_size, void* d_ws, size_t ws_size,
                              hipStream_t stream) {
  const float* x  = (const float*)d_in[0];
  // d_in[1] = experts_capacity_usage: unused by the reference math
  const float* wi = (const float*)d_in[2];
  const float* wo = (const float*)d_in[3];
  float* out = (float*)d_out;

  const size_t WT   = (size_t)E_N * D_N * F_N;       // 8,388,608 elems / weight
  const size_t WT_B = WT * 2;                        // 16 MiB
  unsigned short* wiT = (unsigned short*)d_ws;       // [E][F][D] bf16
  unsigned short* woT = wiT + WT;                    // [E][D][F] bf16
  unsigned short* P   = woT + WT;                    // scratch region
  const size_t baseB = 2 * WT_B;                     // 33,554,432

  const size_t XB_B = (size_t)E_N * ME * D_N * 2;    //  67,108,864 (x as bf16)
  const size_t HF_B = (size_t)E_N * ME * F_N * 2;    // 268,435,456 (full h)
  const size_t HE_B = (size_t)ME * F_N * 2;          //  33,554,432 (per-expert h)
  const size_t HW_B = (size_t)C_N * F_N * 2;         //   4,194,304 (per-(e,w) h)

  const dim3 blk(256);
  const bool haveW = ws_size >= baseB + HW_B;
  if (haveW) {
    transpose_cvt<<<dim3(F_N / 64, D_N / 64, E_N), blk, 0, stream>>>(wi, wiT, D_N, F_N);
    transpose_cvt<<<dim3(D_N / 64, F_N / 64, E_N), blk, 0, stream>>>(wo, woT, F_N, D_N);
  }

  if (ws_size >= baseB + XB_B + HF_B) {
    // Tier A: 5 launches total, all experts batched
    unsigned short* xb = P;
    unsigned short* h  = P + XB_B / 2;
    cvt_x_kernel<<<2048, blk, 0, stream>>>(x, xb, (size_t)E_N * ME * D_N);
    gemm_bt<false, true><<<dim3(ME / 128, F_N / 128, E_N), blk, 0, stream>>>(
        xb, wiT, h, F_N, D_N, (size_t)ME * D_N, (size_t)F_N * D_N, (size_t)ME * F_N);
    gemm_bt<false, false><<<dim3(ME / 128, D_N / 128, E_N), blk, 0, stream>>>(
        h, woT, out, D_N, F_N, (size_t)ME * F_N, (size_t)D_N * F_N, (size_t)ME * D_N);
  } else if (ws_size >= baseB + XB_B + HE_B) {
    // Tier B: per-expert h buffer, reused
    unsigned short* xb = P;
    unsigned short* h  = P + XB_B / 2;
    cvt_x_kernel<<<2048, blk, 0, stream>>>(x, xb, (size_t)E_N * ME * D_N);
    for (int e = 0; e < E_N; ++e) {
      gemm_bt<false, true><<<dim3(ME / 128, F_N / 128, 1), blk, 0, stream>>>(
          xb + (size_t)e * ME * D_N, wiT + (size_t)e * F_N * D_N, h, F_N, D_N, 0, 0, 0);
      gemm_bt<false, false><<<dim3(ME / 128, D_N / 128, 1), blk, 0, stream>>>(
          h, woT + (size_t)e * D_N * F_N, out + (size_t)e * ME * D_N, D_N, F_N, 0, 0, 0);
    }
  } else if (ws_size >= baseB + HE_B) {
    // Tier C: A staged from fp32 x directly (reg-convert)
    unsigned short* h = P;
    for (int e = 0; e < E_N; ++e) {
      gemm_bt<true, true><<<dim3(ME / 128, F_N / 128, 1), blk, 0, stream>>>(
          x + (size_t)e * ME * D_N, wiT + (size_t)e * F_N * D_N, h, F_N, D_N, 0, 0, 0);
      gemm_bt<false, false><<<dim3(ME / 128, D_N / 128, 1), blk, 0, stream>>>(
          h, woT + (size_t)e * D_N * F_N, out + (size_t)e * ME * D_N, D_N, F_N, 0, 0, 0);
    }
  } else if (haveW) {
    // Tier D: per-(e,w) h chunks, M=1024 per GEMM
    unsigned short* h = P;
    for (int e = 0; e < E_N; ++e)
      for (int w = 0; w < W_N; ++w) {
        const float* xa = x + ((size_t)e * W_N + w) * C_N * D_N;
        float* oa = out + ((size_t)e * W_N + w) * C_N * D_N;
        gemm_bt<true, true><<<dim3(C_N / 128, F_N / 128, 1), blk, 0, stream>>>(
            xa, wiT + (size_t)e * F_N * D_N, h, F_N, D_N, 0, 0, 0);
        gemm_bt<false, false><<<dim3(C_N / 128, D_N / 128, 1), blk, 0, stream>>>(
            h, woT + (size_t)e * D_N * F_N, oa, D_N, F_N, 0, 0, 0);
      }
  } else {
    // Tier E: zero-workspace exact-fp32 fallback
    fused_naive<<<dim3(E_N * W_N * C_N), blk, 0, stream>>>(x, wi, wo, out);
  }
}

// Round 2
// 400.583 us; speedup vs baseline: 1.3975x; 1.3975x over previous
//
#include <hip/hip_runtime.h>
#include <hip/hip_bf16.h>
#include <stdint.h>

// LocalExperts grouped FFN: out[e] = relu(x[e] @ wi[e]) @ wo[e]
// E=8, M=W*C=8192 rows/expert, D=512, F=2048. fp32 in/out.
// bf16 MFMA 16x16x32, fp32 accum. 256x256 8-phase schedule (T2+T3+T4+T5).

#define E_N 8
#define W_N 8
#define C_N 1024
#define D_N 512
#define F_N 2048
#define ME  (W_N * C_N)   // 8192 rows per expert

typedef __attribute__((ext_vector_type(4))) float f32x4;
typedef __attribute__((ext_vector_type(8))) short s16x8;

#define BAR()  __builtin_amdgcn_s_barrier()
#define SBAR() __builtin_amdgcn_sched_barrier(0)
#define LGKM0() do { asm volatile("s_waitcnt lgkmcnt(0)" ::: "memory"); SBAR(); } while (0)
#define VM8()   do { asm volatile("s_waitcnt vmcnt(8)"   ::: "memory"); SBAR(); } while (0)
#define VM0()   do { asm volatile("s_waitcnt vmcnt(0)"   ::: "memory"); SBAR(); } while (0)

__device__ __forceinline__ unsigned short f2bf(float f) {
  union { float f; unsigned int u; } v; v.f = f;
  unsigned int u = v.u + 0x7fffu + ((v.u >> 16) & 1u);  // RNE
  return (unsigned short)(u >> 16);
}

__device__ __forceinline__ void gload_lds16(void* lds, const void* g) {
  __builtin_amdgcn_global_load_lds(
      (const __attribute__((address_space(1))) unsigned int*)g,
      (__attribute__((address_space(3))) unsigned int*)lds, 16, 0, 0);
}

// Transpose + fp32->bf16: in [e][R][C] fp32 -> out [e][C][R] bf16
__global__ __launch_bounds__(256)
void transpose_cvt(const float* __restrict__ in, unsigned short* __restrict__ out,
                   int R, int Ccols) {
  __shared__ unsigned short tile[64][65];
  const int e = blockIdx.z;
  const float* ip = in + (size_t)e * R * Ccols;
  unsigned short* op = out + (size_t)e * R * Ccols;
  const int c0 = blockIdx.x * 64, r0 = blockIdx.y * 64;
  const int t = threadIdx.x;
  const int cl = (t & 15) * 4, rw = t >> 4;
#pragma unroll
  for (int i = 0; i < 4; ++i) {
    int row = rw + i * 16;
    float4 v = *(const float4*)&ip[(size_t)(r0 + row) * Ccols + c0 + cl];
    tile[row][cl + 0] = f2bf(v.x);
    tile[row][cl + 1] = f2bf(v.y);
    tile[row][cl + 2] = f2bf(v.z);
    tile[row][cl + 3] = f2bf(v.w);
  }
  __syncthreads();
#pragma unroll
  for (int i = 0; i < 4; ++i) {
    int oc = rw + i * 16;
    ushort4 o;
    o.x = tile[cl + 0][oc];
    o.y = tile[cl + 1][oc];
    o.z = tile[cl + 2][oc];
    o.w = tile[cl + 3][oc];
    *(ushort4*)&op[(size_t)(c0 + oc) * R + r0 + cl] = o;
  }
}

// fp32 -> bf16 elementwise (n multiple of 8)
__global__ __launch_bounds__(256)
void cvt_x_kernel(const float* __restrict__ in, unsigned short* __restrict__ out, size_t n) {
  size_t idx = ((size_t)blockIdx.x * 256 + threadIdx.x) * 8;
  const size_t stride = (size_t)gridDim.x * 256 * 8;
  for (; idx < n; idx += stride) {
    float4 a = *(const float4*)&in[idx];
    float4 b = *(const float4*)&in[idx + 4];
    union { s16x8 v; unsigned short u[8]; } p;
    p.u[0] = f2bf(a.x); p.u[1] = f2bf(a.y); p.u[2] = f2bf(a.z); p.u[3] = f2bf(a.w);
    p.u[4] = f2bf(b.x); p.u[5] = f2bf(b.y); p.u[6] = f2bf(b.z); p.u[7] = f2bf(b.w);
    *(s16x8*)&out[idx] = p.v;
  }
}

// C[M,N] = A[M,K] @ Bt[N,K]^T, bf16 in, fp32 acc.
// 256x256 tile, BK=64 per K-tile, 2 K-tiles/iter, 8 phases/iter.
// 512 threads = 8 waves (2M x 4N); per-wave output 128x64 (8x4 16x16 frags).
// LDS 128 KiB dynamic: [buf2][A/B][half2][128 rows][64 cols] bf16,
// XOR-swizzled at 16B-granule: g_phys = g_log ^ (row&7) (both-sides involution:
// pre-swizzled global stage source + swizzled ds_read addr; gload_lds dest linear).
// vmcnt(8) once per K-tile (8 staged loads/thread/K-tile stay in flight).
template<bool RELU_BF16_OUT>
__global__ __launch_bounds__(512, 2)
void gemm256(const unsigned short* __restrict__ Abase,
             const unsigned short* __restrict__ Btbase,
             void* __restrict__ Cv, int N, int K,
             size_t aStrideE, size_t bStrideE, size_t cStrideE) {
  extern __shared__ unsigned short lds[];
  unsigned char* ldsb = (unsigned char*)lds;
  const int e = blockIdx.z;
  const int m0 = blockIdx.x * 256;
  const int n0 = blockIdx.y * 256;
  const int tid  = threadIdx.x;
  const int lane = tid & 63;
  const int wave = tid >> 6;
  const int wm = wave >> 2;   // 0..1 : A-half / row-half of C
  const int wn = wave & 3;    // 0..3 : 64-col slice of C
  const unsigned short* A  = Abase  + (size_t)e * aStrideE;
  const unsigned short* Bt = Btbase + (size_t)e * bStrideE;

  const int NK = K >> 6;      // 64-wide K-tiles
  const int NI = NK >> 1;     // iterations (2 K-tiles each); requires NI >= 2

  // ---- per-thread ds_read addressing (bytes) ----
  const int rl = lane & 15;           // row-in-frag
  const int gb = lane >> 4;           // 16B-granule base within ks-group
  const int g16_0 = ((0 * 4 + gb) ^ (rl & 7)) * 16;
  const int g16_1 = ((1 * 4 + gb) ^ (rl & 7)) * 16;
  const int aBase0 = wm * 16384 + rl * 128;                                // + buf*65536
  const int bBase0 = 32768 + (wn >> 1) * 16384 + ((wn & 1) * 64 + rl) * 128;

  // ---- per-thread stage addressing (pre-swizzled global source) ----
  int rOffA[2], rOffB[2];
#pragma unroll
  for (int o = 0; o < 2; ++o) {
    int G = o * 512 + tid;            // physical LDS granule within half-tile
    int r = G >> 3;                   // row 0..127
    int gl = (G & 7) ^ (r & 7);       // logical granule (inverse swizzle)
    rOffA[o] = (m0 + r) * K + gl * 8;
    rOffB[o] = (n0 + r) * K + gl * 8;
  }
  // stage one half-tile (128 rows x 64 cols): 2 gload_lds16 per thread
  auto stageA = [&](int kt, int h) {
    const int buf = kt & 1;
#pragma unroll
    for (int o = 0; o < 2; ++o)
      gload_lds16(ldsb + buf * 65536 + h * 16384 + o * 8192 + wave * 1024,
                  A + rOffA[o] + h * 128 * K + kt * 64);
  };
  auto stageB = [&](int kt, int h) {
    const int buf = kt & 1;
#pragma unroll
    for (int o = 0; o < 2; ++o)
      gload_lds16(ldsb + buf * 65536 + 32768 + h * 16384 + o * 8192 + wave * 1024,
                  Bt + rOffB[o] + h * 128 * K + kt * 64);
  };

  f32x4 acc[8][4] = {};

  // ---- prologue: stage K-tiles 0 and 1 (B halves then A halves each) ----
  stageB(0, 0); stageB(0, 1); stageA(0, 0); stageA(0, 1);
  stageB(1, 0); stageB(1, 1); stageA(1, 0); stageA(1, 1);
  VM8();            // kt0 landed (kt1's 8 loads stay in flight)
  BAR();

  // ---- one K-tile: 4 phases {Pa,Pb,Pc,Pd}, 16 MFMA each ----
  auto run_ktile = [&](int buf, int ktN, bool more, bool needDrain) {
    const int bufOff = buf * 65536;
    s16x8 afr[4][2], b01[2][2], b23[2][2];
    // -- Pa: read A m0-3 (8) + B n0-1 (4); MFMA m0-3 x n0-1 --
#pragma unroll
    for (int mi = 0; mi < 4; ++mi) {
      afr[mi][0] = *(const s16x8*)(ldsb + bufOff + aBase0 + mi * 2048 + g16_0);
      afr[mi][1] = *(const s16x8*)(ldsb + bufOff + aBase0 + mi * 2048 + g16_1);
    }
#pragma unroll
    for (int ni = 0; ni < 2; ++ni) {
      b01[ni][0] = *(const s16x8*)(ldsb + bufOff + bBase0 + ni * 2048 + g16_0);
      b01[ni][1] = *(const s16x8*)(ldsb + bufOff + bBase0 + ni * 2048 + g16_1);
    }
    BAR(); LGKM0();
    __builtin_amdgcn_s_setprio(1);
#pragma unroll
    for (int mi = 0; mi < 4; ++mi)
#pragma unroll
      for (int ni = 0; ni < 2; ++ni) {
        acc[mi][ni] = __builtin_amdgcn_mfma_f32_16x16x32_bf16(afr[mi][0], b01[ni][0], acc[mi][ni], 0, 0, 0);
        acc[mi][ni] = __builtin_amdgcn_mfma_f32_16x16x32_bf16(afr[mi][1], b01[ni][1], acc[mi][ni], 0, 0, 0);
      }
    __builtin_amdgcn_s_setprio(0);
    BAR();
    // -- Pb: read B n2-3 (4); MFMA m0-3 x n2-3 --
#pragma unroll
    for (int ni = 0; ni < 2; ++ni) {
      b23[ni][0] = *(const s16x8*)(ldsb + bufOff + bBase0 + (2 + ni) * 2048 + g16_0);
      b23[ni][1] = *(const s16x8*)(ldsb + bufOff + bBase0 + (2 + ni) * 2048 + g16_1);
    }
    BAR(); LGKM0();
    __builtin_amdgcn_s_setprio(1);
#pragma unroll
    for (int mi = 0; mi < 4; ++mi)
#pragma unroll
      for (int ni = 0; ni < 2; ++ni) {
        acc[mi][2 + ni] = __builtin_amdgcn_mfma_f32_16x16x32_bf16(afr[mi][0], b23[ni][0], acc[mi][2 + ni], 0, 0, 0);
        acc[mi][2 + ni] = __builtin_amdgcn_mfma_f32_16x16x32_bf16(afr[mi][1], b23[ni][1], acc[mi][2 + ni], 0, 0, 0);
      }
    __builtin_amdgcn_s_setprio(0);
    BAR();
    // -- Pc: read A m4-7 (8); stage B halves of ktN; MFMA m4-7 x n2-3 --
    //    (all waves' B-reads of this buf completed at Pb's closing barrier)
#pragma unroll
    for (int mi = 0; mi < 4; ++mi) {
      afr[mi][0] = *(const s16x8*)(ldsb + bufOff + aBase0 + (4 + mi) * 2048 + g16_0);
      afr[mi][1] = *(const s16x8*)(ldsb + bufOff + aBase0 + (4 + mi) * 2048 + g16_1);
    }
    if (more) { stageB(ktN, 0); stageB(ktN, 1); }
    BAR(); LGKM0();
    __builtin_amdgcn_s_setprio(1);
#pragma unroll
    for (int mi = 0; mi < 4; ++mi)
#pragma unroll
      for (int ni = 0; ni < 2; ++ni) {
        acc[4 + mi][2 + ni] = __builtin_amdgcn_mfma_f32_16x16x32_bf16(afr[mi][0], b23[ni][0], acc[4 + mi][2 + ni], 0, 0, 0);
        acc[4 + mi][2 + ni] = __builtin_amdgcn_mfma_f32_16x16x32_bf16(afr[mi][1], b23[ni][1], acc[4 + mi][2 + ni], 0, 0, 0);
      }
    __builtin_amdgcn_s_setprio(0);
    BAR();
    // -- Pd: stage A halves of ktN (A-reads done at Pc close); MFMA m4-7 x n0-1;
    //        counted vmcnt before closing barrier (once per K-tile) --
    if (more) { stageA(ktN, 0); stageA(ktN, 1); }
    BAR();
    __builtin_amdgcn_s_setprio(1);
#pragma unroll
    for (int mi = 0; mi < 4; ++mi)
#pragma unroll
      for (int ni = 0; ni < 2; ++ni) {
        acc[4 + mi][ni] = __builtin_amdgcn_mfma_f32_16x16x32_bf16(afr[mi][0], b01[ni][0], acc[4 + mi][ni], 0, 0, 0);
        acc[4 + mi][ni] = __builtin_amdgcn_mfma_f32_16x16x32_bf16(afr[mi][1], b01[ni][1], acc[4 + mi][ni], 0, 0, 0);
      }
    __builtin_amdgcn_s_setprio(0);
    if (more) { VM8(); } else if (needDrain) { VM0(); }
    BAR();
  };

  for (int i = 0; i < NI; ++i) {
    const bool more = (i + 1 < NI);
    run_ktile(0, 2 * i + 2, more, true);
    run_ktile(1, 2 * i + 3, more, false);
  }

  // ---- epilogue: C/D layout col=lane&15, row=(lane>>4)*4+reg (m89/m91) ----
  const int rq = (lane >> 4) * 4;
  const int cq = lane & 15;
  if (RELU_BF16_OUT) {
    unsigned short* Cb = (unsigned short*)Cv + (size_t)e * cStrideE;
#pragma unroll
    for (int mi = 0; mi < 8; ++mi)
#pragma unroll
      for (int ni = 0; ni < 4; ++ni) {
        int row0 = m0 + wm * 128 + mi * 16 + rq;
        int col  = n0 + wn * 64 + ni * 16 + cq;
#pragma unroll
        for (int r = 0; r < 4; ++r) {
          float v = acc[mi][ni][r];
          v = v > 0.f ? v : 0.f;
          Cb[(size_t)(row0 + r) * N + col] = f2bf(v);
        }
      }
  } else {
    float* Cf = (float*)Cv + (size_t)e * cStrideE;
#pragma unroll
    for (int mi = 0; mi < 8; ++mi)
#pragma unroll
      for (int ni = 0; ni < 4; ++ni) {
        int row0 = m0 + wm * 128 + mi * 16 + rq;
        int col  = n0 + wn * 64 + ni * 16 + cq;
#pragma unroll
        for (int r = 0; r < 4; ++r)
          Cf[(size_t)(row0 + r) * N + col] = acc[mi][ni][r];
      }
  }
}

// Zero-workspace fp32 fallback (correct, slow). One block per token row.
__global__ __launch_bounds__(256)
void fused_naive(const float* __restrict__ x, const float* __restrict__ wi,
                 const float* __restrict__ wo, float* __restrict__ out) {
  __shared__ float xs[D_N];
  __shared__ float hs[F_N];
  const size_t row = blockIdx.x;
  const int e = (int)(row / (W_N * C_N));
  const float* xr = x + row * D_N;
  const float* wie = wi + (size_t)e * D_N * F_N;
  const float* woe = wo + (size_t)e * F_N * D_N;
  const int t = threadIdx.x;
  for (int d = t; d < D_N; d += 256) xs[d] = xr[d];
  __syncthreads();
  for (int f = t; f < F_N; f += 256) {
    float a = 0.f;
    for (int d = 0; d < D_N; ++d) a += xs[d] * wie[(size_t)d * F_N + f];
    hs[f] = a > 0.f ? a : 0.f;
  }
  __syncthreads();
  float* orow = out + row * D_N;
  for (int d = t; d < D_N; d += 256) {
    float a = 0.f;
    for (int f = 0; f < F_N; ++f) a += hs[f] * woe[(size_t)f * D_N + d];
    orow[d] = a;
  }
}

extern "C" void kernel_launch(void* const* d_in, const int* in_sizes, int n_in,
                              void* d_out, int out_size, void* d_ws, size_t ws_size,
                              hipStream_t stream) {
  const float* x  = (const float*)d_in[0];
  // d_in[1] = experts_capacity_usage: unused by the reference math
  const float* wi = (const float*)d_in[2];
  const float* wo = (const float*)d_in[3];
  float* out = (float*)d_out;

  const size_t WT   = (size_t)E_N * D_N * F_N;       // elems per weight tensor
  unsigned short* wiT = (unsigned short*)d_ws;       // [E][F][D] bf16
  unsigned short* woT = wiT + WT;                    // [E][D][F] bf16
  unsigned short* P   = woT + WT;
  const size_t baseB = 2 * WT * 2;                   // 32 MiB
  const size_t XB_B  = (size_t)E_N * ME * D_N * 2;   // x as bf16
  const size_t HF_B  = (size_t)E_N * ME * F_N * 2;   // full h

  const dim3 blk(256);
  if (ws_size >= baseB + XB_B + HF_B) {
    hipFuncSetAttribute(reinterpret_cast<const void*>(gemm256<true>),
                        hipFuncAttributeMaxDynamicSharedMemorySize, 131072);
    hipFuncSetAttribute(reinterpret_cast<const void*>(gemm256<false>),
                        hipFuncAttributeMaxDynamicSharedMemorySize, 131072);
    transpose_cvt<<<dim3(F_N / 64, D_N / 64, E_N), blk, 0, stream>>>(wi, wiT, D_N, F_N);
    transpose_cvt<<<dim3(D_N / 64, F_N / 64, E_N), blk, 0, stream>>>(wo, woT, F_N, D_N);
    unsigned short* xb = P;
    unsigned short* h  = P + XB_B / 2;
    cvt_x_kernel<<<2048, blk, 0, stream>>>(x, xb, (size_t)E_N * ME * D_N);
    gemm256<true><<<dim3(ME / 256, F_N / 256, E_N), dim3(512), 131072, stream>>>(
        xb, wiT, h, F_N, D_N, (size_t)ME * D_N, (size_t)F_N * D_N, (size_t)ME * F_N);
    gemm256<false><<<dim3(ME / 256, D_N / 256, E_N), dim3(512), 131072, stream>>>(
        h, woT, out, D_N, F_N, (size_t)ME * F_N, (size_t)D_N * F_N, (size_t)ME * D_N);
  } else {
    fused_naive<<<dim3(E_N * W_N * C_N), blk, 0, stream>>>(x, wi, wo, out);
  }
}